// Round 1
// baseline (10508.350 us; speedup 1.0000x reference)
//
#include <hip/hip_runtime.h>
#include <math.h>

constexpr int TS = 4;     // samples per block
constexpr int NT = 256;   // threads per block
constexpr int H0 = 768;   // HID0 dim per sample
constexpr int H1 = 1536;  // HID1 dim per sample

// ============================================================================
// Clebsch-Gordan init (device fp64, exact translation of reference python)
// ============================================================================
__device__ inline double dfact(int n){ double r=1.0; for(int i=2;i<=n;i++) r*=(double)i; return r; }

__device__ void real_to_complex_U(int l, double* Ur, double* Ui){
  int d=2*l+1;
  for(int i=0;i<d*d;i++){Ur[i]=0.0;Ui[i]=0.0;}
  Ur[l*d+l]=1.0;
  double s=1.0/sqrt(2.0);
  for(int m=1;m<=l;m++){
    double sgn=(m&1)?-1.0:1.0;
    Ur[(l-m)*d+(l+m)] = s;
    Ur[(l+m)*d+(l+m)] = sgn*s;
    Ui[(l-m)*d+(l-m)] = s;
    Ui[(l+m)*d+(l-m)] = -sgn*s;
  }
  // multiply by (-1j)^l
  double pr,pi; int lm=l&3;
  if(lm==0){pr=1;pi=0;} else if(lm==1){pr=0;pi=-1;} else if(lm==2){pr=-1;pi=0;} else {pr=0;pi=1;}
  for(int i=0;i<d*d;i++){
    double r=Ur[i],im=Ui[i];
    Ur[i]=r*pr-im*pi;
    Ui[i]=r*pi+im*pr;
  }
}

__device__ void compute_real_cg(int l1,int l2,int l3, float* out){
  int d1=2*l1+1,d2=2*l2+1,d3=2*l3+1;
  double C[125];
  for(int i=0;i<d1*d2*d3;i++) C[i]=0.0;
  for(int m1=-l1;m1<=l1;m1++)for(int m2=-l2;m2<=l2;m2++){
    int m3=m1+m2;
    if(m3<-l3||m3>l3) continue;
    double pref = sqrt((double)(2*l3+1)*dfact(l3+l1-l2)*dfact(l3-l1+l2)*dfact(l1+l2-l3)/dfact(l1+l2+l3+1));
    pref *= sqrt(dfact(l3+m3)*dfact(l3-m3)*dfact(l1-m1)*dfact(l1+m1)*dfact(l2-m2)*dfact(l2+m2));
    double s=0.0;
    for(int k=0;k<=l1+l2-l3;k++){
      int a0=k, a1=l1+l2-l3-k, a2=l1-m1-k, a3=l2+m2-k, a4=l3-l2+m1+k, a5=l3-l1-m2+k;
      if(a0<0||a1<0||a2<0||a3<0||a4<0||a5<0) continue;
      double t=1.0/(dfact(a0)*dfact(a1)*dfact(a2)*dfact(a3)*dfact(a4)*dfact(a5));
      s += (k&1)? -t : t;
    }
    C[((m1+l1)*d2+(m2+l2))*d3+(m3+l3)] = pref*s;
  }
  double U1r[25],U1i[25],U2r[25],U2i[25],U3r[25],U3i[25];
  real_to_complex_U(l1,U1r,U1i);
  real_to_complex_U(l2,U2r,U2i);
  real_to_complex_U(l3,U3r,U3i);
  double Kr[125],Ki[125];
  for(int a=0;a<d1;a++)for(int b=0;b<d2;b++)for(int c=0;c<d3;c++){
    double sr=0.0,si=0.0;
    for(int m=0;m<d1;m++)for(int n2=0;n2<d2;n2++){
      double u1r=U1r[m*d1+a],u1i=U1i[m*d1+a];
      double u2r=U2r[n2*d2+b],u2i=U2i[n2*d2+b];
      double t12r=u1r*u2r-u1i*u2i, t12i=u1r*u2i+u1i*u2r;
      for(int o=0;o<d3;o++){
        double cv=C[(m*d2+n2)*d3+o];
        if(cv==0.0) continue;
        double u3r=U3r[o*d3+c],u3i=-U3i[o*d3+c]; // conj
        double tr=t12r*u3r - t12i*u3i, ti=t12r*u3i + t12i*u3r;
        sr += tr*cv; si += ti*cv;
      }
    }
    Kr[(a*d2+b)*d3+c]=sr; Ki[(a*d2+b)*d3+c]=si;
  }
  int sz=d1*d2*d3;
  double nr=0,ni=0;
  for(int i=0;i<sz;i++){nr+=Kr[i]*Kr[i]; ni+=Ki[i]*Ki[i];}
  const double* K = (nr>=ni)? Kr:Ki;
  double nrm = sqrt((nr>=ni)?nr:ni);
  double sc = sqrt((double)(2*l3+1))/nrm;
  for(int i=0;i<sz;i++) out[i]=(float)(K[i]*sc);
}

// combo table: idx:(l1,l2,l3)->offset
// 0:(0,0,0)@0  1:(0,1,1)@1  2:(1,0,1)@10 3:(0,2,2)@19 4:(2,0,2)@44 5:(1,1,0)@69
// 6:(1,1,1)@78 7:(1,1,2)@105 8:(2,1,2)@150 9:(1,2,2)@225 10:(2,2,0)@300
// 11:(2,2,1)@325 12:(2,2,2)@400 ; total 525 floats
__global__ void cg_init_kernel(float* cg){
  if(threadIdx.x!=0||blockIdx.x!=0) return;
  const int L1[13]={0,0,1,0,2,1,1,1,2,1,2,2,2};
  const int L2[13]={0,1,0,2,0,1,1,1,1,2,2,2,2};
  const int L3[13]={0,1,1,2,2,0,1,2,2,2,0,1,2};
  const int OFF[13]={0,1,10,19,44,69,78,105,150,225,300,325,400};
  for(int c=0;c<13;c++) compute_real_cg(L1[c],L2[c],L3[c], cg+OFF[c]);
}

// ============================================================================
// Main fused kernel
// ============================================================================
// HID0 block layout per sample (768 floats): l=0 @0 (64), l=1 @64 (64x3),
// l=2 @256 (64x5), l=1 @576 (64x3). Element (u,j) at off + u*(2l+1)+j.
// HID1 layout (1536): l=0 @0 (128), l=1 @128 (128x3), l=2 @512 (128x5), l=1 @1152.

__device__ void lin_h(const float* __restrict__ W0, const float* __restrict__ W1,
                      const float* __restrict__ W2, const float* __restrict__ b0,
                      const float* src, float* dst, int tid)
{
  const float rs128 = 0.08838834764831845f; // 1/sqrt(128)
  // l=0: out u in [0,64)
  for (int idx=tid; idx<TS*64; idx+=NT){
    int u=idx&63, n=idx>>6;
    const float* s=src+n*H0;
    float acc=0.f;
    #pragma unroll 8
    for (int v=0;v<64;v++) acc += s[v]*W0[v*64+u];
    dst[n*H0+u] = acc*0.125f + b0[u];
  }
  // l=1: out u in [0,128) (cols 0:64 -> block1, 64:128 -> block3), j in [0,3)
  for (int idx=tid; idx<TS*384; idx+=NT){
    int u=idx&127, j=(idx>>7)%3, n=idx/384;
    const float* s=src+n*H0;
    float acc=0.f;
    #pragma unroll 8
    for (int v=0;v<64;v++) acc += s[64+v*3+j]*W1[v*128+u];
    #pragma unroll 8
    for (int v=0;v<64;v++) acc += s[576+v*3+j]*W1[(v+64)*128+u];
    int du = (u<64)? (64+u*3+j) : (576+(u-64)*3+j);
    dst[n*H0+du] = acc*rs128;
  }
  // l=2
  for (int idx=tid; idx<TS*320; idx+=NT){
    int u=idx&63, j=(idx>>6)%5, n=idx/320;
    const float* s=src+n*H0;
    float acc=0.f;
    #pragma unroll 8
    for (int v=0;v<64;v++) acc += s[256+v*5+j]*W2[v*64+u];
    dst[n*H0+256+u*5+j] = acc*0.125f;
  }
}

// uvu tensor-product path: b[n,u,j]=sum_v w[u,v]*x2[n,v,j]; t[n,u,k]=sum_ij x1[n,u,i]*b[n,u,j]*K[i,j,k]
template<int D1,int D2,int D3,int O1,int O2,int O3,int CGO>
__device__ __forceinline__ void uvu_path(const float* __restrict__ wp,
    const float* s1, const float* s2, float* dst,
    float* s_w, float* s_b, const float* s_cg, int tid)
{
  __syncthreads();  // prev path's contraction (and initial zeroing) complete
  for (int i=tid;i<4096;i+=NT) s_w[(i>>6)*65+(i&63)] = wp[i];
  __syncthreads();
  constexpr int NB = TS*64*D2;
  for (int idx=tid; idx<NB; idx+=NT){
    int j = idx % D2, rr = idx / D2;
    int u = rr & 63, n = rr >> 6;
    const float* s2p = s2 + n*H0 + O2 + j;
    const float* wr = s_w + u*65;
    float acc=0.f;
    #pragma unroll 8
    for (int v=0;v<64;v++) acc += wr[v]*s2p[v*D2];
    s_b[rr*D2+j] = acc;
  }
  __syncthreads();
  {
    int u = tid & 63, n = tid >> 6;
    float x1v[D1], bv[D2], tk[D3];
    #pragma unroll
    for (int i=0;i<D1;i++) x1v[i] = s1[n*H0 + O1 + u*D1 + i];
    #pragma unroll
    for (int j=0;j<D2;j++) bv[j] = s_b[(n*64+u)*D2 + j];
    #pragma unroll
    for (int k=0;k<D3;k++) tk[k]=0.f;
    #pragma unroll
    for (int i=0;i<D1;i++){
      #pragma unroll
      for (int j=0;j<D2;j++){
        float pr = x1v[i]*bv[j];
        #pragma unroll
        for (int k=0;k<D3;k++) tk[k] += pr*s_cg[CGO+(i*D2+j)*D3+k];
      }
    }
    float* dp = dst + n*H0 + O3 + u*D3;
    #pragma unroll
    for (int k=0;k<D3;k++) dp[k] += tk[k];  // unique owner (n,u) -> no race
  }
}

__device__ void tp_uvu_all(const float* tw, const float* s1, const float* s2, float* dst,
                           float* s_w, float* s_b, const float* s_cg, int tid)
{
  for (int i=tid;i<TS*H0;i+=NT) dst[i]=0.f;
  uvu_path<1,1,1,  0,  0,  0,  0>(tw+ 0*4096, s1,s2,dst,s_w,s_b,s_cg,tid);
  uvu_path<1,3,3,  0, 64, 64,  1>(tw+ 1*4096, s1,s2,dst,s_w,s_b,s_cg,tid);
  uvu_path<1,5,5,  0,256,256, 19>(tw+ 2*4096, s1,s2,dst,s_w,s_b,s_cg,tid);
  uvu_path<1,3,3,  0,576,576,  1>(tw+ 3*4096, s1,s2,dst,s_w,s_b,s_cg,tid);
  uvu_path<3,1,3, 64,  0, 64, 10>(tw+ 4*4096, s1,s2,dst,s_w,s_b,s_cg,tid);
  uvu_path<3,3,1, 64, 64,  0, 69>(tw+ 5*4096, s1,s2,dst,s_w,s_b,s_cg,tid);
  uvu_path<3,3,3, 64, 64, 64, 78>(tw+ 6*4096, s1,s2,dst,s_w,s_b,s_cg,tid);
  uvu_path<3,3,3, 64, 64,576, 78>(tw+ 7*4096, s1,s2,dst,s_w,s_b,s_cg,tid);
  uvu_path<5,1,5,256,  0,256, 44>(tw+ 8*4096, s1,s2,dst,s_w,s_b,s_cg,tid);
  uvu_path<5,3,5,256, 64,256,150>(tw+ 9*4096, s1,s2,dst,s_w,s_b,s_cg,tid);
  uvu_path<5,5,1,256,256,  0,300>(tw+10*4096, s1,s2,dst,s_w,s_b,s_cg,tid);
  uvu_path<5,5,3,256,256, 64,325>(tw+11*4096, s1,s2,dst,s_w,s_b,s_cg,tid);
  uvu_path<5,5,3,256,256,576,325>(tw+12*4096, s1,s2,dst,s_w,s_b,s_cg,tid);
  uvu_path<5,3,5,256,576,256,150>(tw+13*4096, s1,s2,dst,s_w,s_b,s_cg,tid);
  __syncthreads();
  // fan normalization: io0(fan 192) r<64 ; io1,io2(fan 256) 64<=r<576 ; io3(fan 192) r>=576
  for (int idx=tid; idx<TS*H0; idx+=NT){
    int r = idx % H0;
    float scl = (r<64 || r>=576)? 0.07216878364870323f : 0.0625f;
    dst[idx] *= scl;
  }
}

// fully-connected TP path: sum over u too (out mul = 1)
template<int D1,int D2,int D3,int O1,int O2,int IOB,int CGO>
__device__ __forceinline__ void fc_path(const float* __restrict__ wp,
    const float* s1, const float* s2, float* s_out,
    float* s_w, float* s_b, const float* s_cg, int tid)
{
  __syncthreads();
  for (int i=tid;i<4096;i+=NT) s_w[(i>>6)*65+(i&63)] = wp[i];
  __syncthreads();
  constexpr int NB = TS*64*D2;
  for (int idx=tid; idx<NB; idx+=NT){
    int j = idx % D2, rr = idx / D2;
    int u = rr & 63, n = rr >> 6;
    const float* s2p = s2 + n*H0 + O2 + j;
    const float* wr = s_w + u*65;
    float acc=0.f;
    #pragma unroll 8
    for (int v=0;v<64;v++) acc += wr[v]*s2p[v*D2];
    s_b[rr*D2+j] = acc;
  }
  __syncthreads();
  {
    int u = tid & 63, n = tid >> 6;  // one wave per sample
    float x1v[D1], bv[D2], tk[D3];
    #pragma unroll
    for (int i=0;i<D1;i++) x1v[i] = s1[n*H0 + O1 + u*D1 + i];
    #pragma unroll
    for (int j=0;j<D2;j++) bv[j] = s_b[(n*64+u)*D2 + j];
    #pragma unroll
    for (int k=0;k<D3;k++) tk[k]=0.f;
    #pragma unroll
    for (int i=0;i<D1;i++){
      #pragma unroll
      for (int j=0;j<D2;j++){
        float pr = x1v[i]*bv[j];
        #pragma unroll
        for (int k=0;k<D3;k++) tk[k] += pr*s_cg[CGO+(i*D2+j)*D3+k];
      }
    }
    #pragma unroll
    for (int k=0;k<D3;k++){
      float v = tk[k];
      v += __shfl_down(v, 32, 64);
      v += __shfl_down(v, 16, 64);
      v += __shfl_down(v,  8, 64);
      v += __shfl_down(v,  4, 64);
      v += __shfl_down(v,  2, 64);
      v += __shfl_down(v,  1, 64);
      if (u==0) s_out[n*6 + IOB + k] += v;  // lane0 of wave n, unique owner per path
    }
  }
}

__global__ __launch_bounds__(NT) void deeprst_main(
    const float* __restrict__ x,
    const float* __restrict__ l1W0, const float* __restrict__ l1W1,
    const float* __restrict__ l1W2, const float* __restrict__ l1b0,
    const float* __restrict__ l2W0, const float* __restrict__ l2W1,
    const float* __restrict__ l2W2, const float* __restrict__ l2b0,
    const float* __restrict__ LW0, const float* __restrict__ LW1,
    const float* __restrict__ LW2, const float* __restrict__ Lb0,
    const float* __restrict__ tpw, const float* __restrict__ tp4w,
    const float* __restrict__ cg, float* __restrict__ out)
{
  __shared__ float sA[3*TS*H0];   // 9216 floats: 3 rotating state buffers
  __shared__ float s_w[64*65];    // padded path-weight tile
  __shared__ float s_b[TS*64*5];  // tp intermediate b
  __shared__ float s_cg[525];     // CG tables
  __shared__ float s_out[TS*6];   // fc-TP output accumulator

  const int tid = threadIdx.x;
  const int n0 = blockIdx.x * TS;
  const float rs128 = 0.08838834764831845f;
  const float rs8   = 0.3535533905932738f;

  for (int i=tid;i<525;i+=NT) s_cg[i]=cg[i];
  if (tid<TS*6) s_out[tid]=0.f;

  float* h1 = sA;              // 4*1536 floats (occupies buffers 0+1)
  float* B2 = sA + 2*TS*H0;

  // ---- lin1: x (IRREPS_IN) -> h1 (HID1) ----
  for (int idx=tid; idx<TS*128; idx+=NT){
    int u=idx&127, n=idx>>7;
    const float* xp = x + (n0+n)*80;
    float acc=0.f;
    #pragma unroll
    for (int v=0;v<16;v++) acc += xp[v]*l1W0[v*128+u];
    h1[n*H1+u] = acc*0.25f + l1b0[u];
  }
  for (int idx=tid; idx<TS*768; idx+=NT){
    int u=idx&255, j=(idx>>8)%3, n=idx/768;
    const float* xp = x + (n0+n)*80 + 16;
    float acc=0.f;
    #pragma unroll
    for (int v=0;v<8;v++) acc += xp[v*3+j]*l1W1[v*256+u];
    int du = (u<128)? (128+u*3+j) : (1152+(u-128)*3+j);
    h1[n*H1+du] = acc*rs8;
  }
  for (int idx=tid; idx<TS*640; idx+=NT){
    int u=idx&127, j=(idx>>7)%5, n=idx/640;
    const float* xp = x + (n0+n)*80 + 40;
    float acc=0.f;
    #pragma unroll
    for (int v=0;v<8;v++) acc += xp[v*5+j]*l1W2[v*128+u];
    h1[n*H1+512+u*5+j] = acc*rs8;
  }
  __syncthreads();

  // ---- lin2: h1 (HID1) -> B2 (HID0) ----
  for (int idx=tid; idx<TS*64; idx+=NT){
    int u=idx&63, n=idx>>6;
    const float* s=h1+n*H1;
    float acc=0.f;
    #pragma unroll 8
    for (int v=0;v<128;v++) acc += s[v]*l2W0[v*64+u];
    B2[n*H0+u] = acc*rs128 + l2b0[u];
  }
  for (int idx=tid; idx<TS*384; idx+=NT){
    int u=idx&127, j=(idx>>7)%3, n=idx/384;
    const float* s=h1+n*H1;
    float acc=0.f;
    #pragma unroll 8
    for (int v=0;v<128;v++) acc += s[128+v*3+j]*l2W1[v*128+u];
    #pragma unroll 8
    for (int v=0;v<128;v++) acc += s[1152+v*3+j]*l2W1[(v+128)*128+u];
    int du=(u<64)?(64+u*3+j):(576+(u-64)*3+j);
    B2[n*H0+du] = acc*0.0625f;
  }
  for (int idx=tid; idx<TS*320; idx+=NT){
    int u=idx&63, j=(idx>>6)%5, n=idx/320;
    const float* s=h1+n*H1;
    float acc=0.f;
    #pragma unroll 8
    for (int v=0;v<128;v++) acc += s[512+v*5+j]*l2W2[v*64+u];
    B2[n*H0+256+u*5+j] = acc*rs128;
  }
  __syncthreads();

  // ---- 3 rounds: split -> tp_uvu -> linear ----
  float* h  = B2;
  float* u0 = sA;
  float* u1 = sA + TS*H0;
  for (int r=0;r<3;r++){
    const float* Wa0=LW0+(3*r  )*4096; const float* Wa1=LW1+(3*r  )*16384;
    const float* Wa2=LW2+(3*r  )*4096; const float* ba =Lb0+(3*r  )*64;
    const float* Wb0=LW0+(3*r+1)*4096; const float* Wb1=LW1+(3*r+1)*16384;
    const float* Wb2=LW2+(3*r+1)*4096; const float* bb =Lb0+(3*r+1)*64;
    const float* Wc0=LW0+(3*r+2)*4096; const float* Wc1=LW1+(3*r+2)*16384;
    const float* Wc2=LW2+(3*r+2)*4096; const float* bc =Lb0+(3*r+2)*64;

    lin_h(Wa0,Wa1,Wa2,ba, h, u0, tid);
    lin_h(Wb0,Wb1,Wb2,bb, h, u1, tid);
    __syncthreads();
    tp_uvu_all(tpw + r*14*4096, u0, u1, h, s_w, s_b, s_cg, tid); // ht overwrites h
    __syncthreads();
    lin_h(Wc0,Wc1,Wc2,bc, h, u0, tid);  // new h into old u0
    __syncthreads();
    float* nh=u0; u0=u1; u1=h; h=nh;
  }

  // ---- split4 + fully-connected TP ----
  lin_h(LW0+9*4096, LW1+9*16384, LW2+9*4096, Lb0+9*64, h, u0, tid);
  lin_h(LW0+10*4096, LW1+10*16384, LW2+10*4096, Lb0+10*64, h, u1, tid);
  __syncthreads();

  fc_path<1,1,1,  0,  0,0,  0>(tp4w+ 0*4096, u0,u1,s_out,s_w,s_b,s_cg,tid);
  fc_path<3,3,1, 64, 64,0, 69>(tp4w+ 1*4096, u0,u1,s_out,s_w,s_b,s_cg,tid);
  fc_path<3,3,1, 64,576,0, 69>(tp4w+ 2*4096, u0,u1,s_out,s_w,s_b,s_cg,tid);
  fc_path<5,5,1,256,256,0,300>(tp4w+ 3*4096, u0,u1,s_out,s_w,s_b,s_cg,tid);
  fc_path<3,3,1,576, 64,0, 69>(tp4w+ 4*4096, u0,u1,s_out,s_w,s_b,s_cg,tid);
  fc_path<3,3,1,576,576,0, 69>(tp4w+ 5*4096, u0,u1,s_out,s_w,s_b,s_cg,tid);
  fc_path<1,5,5,  0,256,1, 19>(tp4w+ 6*4096, u0,u1,s_out,s_w,s_b,s_cg,tid);
  fc_path<3,3,5, 64, 64,1,105>(tp4w+ 7*4096, u0,u1,s_out,s_w,s_b,s_cg,tid);
  fc_path<3,5,5, 64,256,1,225>(tp4w+ 8*4096, u0,u1,s_out,s_w,s_b,s_cg,tid);
  fc_path<3,3,5, 64,576,1,105>(tp4w+ 9*4096, u0,u1,s_out,s_w,s_b,s_cg,tid);
  fc_path<5,1,5,256,  0,1, 44>(tp4w+10*4096, u0,u1,s_out,s_w,s_b,s_cg,tid);
  fc_path<5,3,5,256, 64,1,150>(tp4w+11*4096, u0,u1,s_out,s_w,s_b,s_cg,tid);
  fc_path<5,5,5,256,256,1,400>(tp4w+12*4096, u0,u1,s_out,s_w,s_b,s_cg,tid);
  fc_path<5,3,5,256,576,1,150>(tp4w+13*4096, u0,u1,s_out,s_w,s_b,s_cg,tid);
  fc_path<3,3,5,576, 64,1,105>(tp4w+14*4096, u0,u1,s_out,s_w,s_b,s_cg,tid);
  fc_path<3,5,5,576,256,1,225>(tp4w+15*4096, u0,u1,s_out,s_w,s_b,s_cg,tid);
  fc_path<3,3,5,576,576,1,105>(tp4w+16*4096, u0,u1,s_out,s_w,s_b,s_cg,tid);
  __syncthreads();

  if (tid < TS*6){
    int n=tid/6, k=tid%6;
    float sc = (k==0)? (1.0f/sqrtf(24576.0f)) : (1.0f/sqrtf(45056.0f));
    out[(n0+n)*6+k] = s_out[tid]*sc;
  }
}

// ============================================================================
extern "C" void kernel_launch(void* const* d_in, const int* in_sizes, int n_in,
                              void* d_out, int out_size, void* d_ws, size_t ws_size,
                              hipStream_t stream)
{
  (void)n_in; (void)out_size; (void)ws_size;
  const float* x    = (const float*)d_in[0];
  const float* l1W0 = (const float*)d_in[1];
  const float* l1W1 = (const float*)d_in[2];
  const float* l1W2 = (const float*)d_in[3];
  const float* l1b0 = (const float*)d_in[4];
  const float* l2W0 = (const float*)d_in[5];
  const float* l2W1 = (const float*)d_in[6];
  const float* l2W2 = (const float*)d_in[7];
  const float* l2b0 = (const float*)d_in[8];
  const float* LW0  = (const float*)d_in[9];
  const float* LW1  = (const float*)d_in[10];
  const float* LW2  = (const float*)d_in[11];
  const float* Lb0  = (const float*)d_in[12];
  const float* tpw  = (const float*)d_in[13];
  const float* tp4w = (const float*)d_in[14];
  float* cg = (float*)d_ws;   // 525 floats; ws re-poisoned every launch -> recompute
  const int n = in_sizes[0]/80;

  cg_init_kernel<<<1, 64, 0, stream>>>(cg);
  deeprst_main<<<n/TS, NT, 0, stream>>>(x,l1W0,l1W1,l1W2,l1b0,l2W0,l2W1,l2W2,l2b0,
                                        LW0,LW1,LW2,Lb0,tpw,tp4w,cg,(float*)d_out);
}

// Round 2
// 5541.397 us; speedup vs baseline: 1.8963x; 1.8963x over previous
//
#include <hip/hip_runtime.h>
#include <math.h>

constexpr int TS = 4;     // samples per block
constexpr int NT = 256;   // threads per block
constexpr int H0 = 768;   // HID0 dim per sample
constexpr int H1 = 1536;  // HID1 dim per sample

// ============================================================================
// Clebsch-Gordan init: element-parallel, fp64, registers only.
// combo table: idx:(l1,l2,l3)->offset
// 0:(0,0,0)@0 1:(0,1,1)@1 2:(1,0,1)@10 3:(0,2,2)@19 4:(2,0,2)@44 5:(1,1,0)@69
// 6:(1,1,1)@78 7:(1,1,2)@105 8:(2,1,2)@150 9:(1,2,2)@225 10:(2,2,0)@300
// 11:(2,2,1)@325 12:(2,2,2)@400 ; total 525 floats
// ============================================================================
__device__ inline double dfact(int n){ double r=1.0; for(int i=2;i<=n;i++) r*=(double)i; return r; }

struct dcplx { double x, y; };
__device__ inline dcplx cmul(dcplx a, dcplx b){ return {a.x*b.x-a.y*b.y, a.x*b.y+a.y*b.x}; }

// U[r][c] entry of _real_to_complex(l), including the (-1j)^l phase
__device__ dcplx Uent(int l, int r, int c){
  double re=0.0, im=0.0;
  double s = 1.0/sqrt(2.0);
  if (r==l && c==l) re = 1.0;
  else if (c>l){ int m=c-l; double sgn=(m&1)?-1.0:1.0;
    if (r==l-m) re = s; else if (r==l+m) re = sgn*s;
  } else if (c<l){ int m=l-c; double sgn=(m&1)?-1.0:1.0;
    if (r==l-m) im = s; else if (r==l+m) im = -sgn*s;
  }
  int lm=l&3; double pr,pi;
  if(lm==0){pr=1;pi=0;} else if(lm==1){pr=0;pi=-1;} else if(lm==2){pr=-1;pi=0;} else {pr=0;pi=1;}
  return { re*pr-im*pi, re*pi+im*pr };
}

__device__ double cg_complex_entry(int l1,int l2,int l3,int m1,int m2){
  int m3=m1+m2;
  if (m3<-l3 || m3>l3) return 0.0;
  double pref = sqrt((double)(2*l3+1)*dfact(l3+l1-l2)*dfact(l3-l1+l2)*dfact(l1+l2-l3)/dfact(l1+l2+l3+1));
  pref *= sqrt(dfact(l3+m3)*dfact(l3-m3)*dfact(l1-m1)*dfact(l1+m1)*dfact(l2-m2)*dfact(l2+m2));
  double s=0.0;
  for(int k=0;k<=l1+l2-l3;k++){
    int a2=l1-m1-k, a3=l2+m2-k, a4=l3-l2+m1+k, a5=l3-l1-m2+k;
    if(a2<0||a3<0||a4<0||a5<0) continue;
    double t=1.0/(dfact(k)*dfact(l1+l2-l3-k)*dfact(a2)*dfact(a3)*dfact(a4)*dfact(a5));
    s += (k&1)? -t : t;
  }
  return pref*s;
}

__global__ void cg_init_kernel(float* cg){
  __shared__ double sKr[525], sKi[525];
  __shared__ double sScale[13];
  __shared__ int    sSel[13];
  const int L1[13]={0,0,1,0,2,1,1,1,2,1,2,2,2};
  const int L2[13]={0,1,0,2,0,1,1,1,1,2,2,2,2};
  const int L3[13]={0,1,1,2,2,0,1,2,2,2,0,1,2};
  const int OFF[14]={0,1,10,19,44,69,78,105,150,225,300,325,400,525};
  const int tid = threadIdx.x;
  int combo=-1, l1=0,l2=0,l3=0, e=0;
  if (tid < 525){
    combo=12;
    for(int i=0;i<12;i++) if (tid < OFF[i+1]) { combo=i; break; }
    l1=L1[combo]; l2=L2[combo]; l3=L3[combo];
    int d2=2*l2+1, d3=2*l3+1;
    e = tid - OFF[combo];
    int a = e/(d2*d3), b=(e/d3)%d2, cc=e%d3;
    double kr=0.0, ki=0.0;
    for(int m=0;m<2*l1+1;m++) for(int n=0;n<d2;n++){
      int m3 = (m-l1)+(n-l2);
      if (m3<-l3||m3>l3) continue;
      double cv = cg_complex_entry(l1,l2,l3,m-l1,n-l2);
      if (cv==0.0) continue;
      dcplx u1=Uent(l1,m,a), u2=Uent(l2,n,b), u3=Uent(l3,m3+l3,cc);
      u3.y = -u3.y;  // conj
      dcplx t = cmul(cmul(u1,u2),u3);
      kr += t.x*cv; ki += t.y*cv;
    }
    sKr[tid]=kr; sKi[tid]=ki;
  }
  __syncthreads();
  if (tid < 13){
    int sz = OFF[tid+1]-OFF[tid];
    double nr=0,ni=0;
    for(int i=0;i<sz;i++){ double r=sKr[OFF[tid]+i], im=sKi[OFF[tid]+i]; nr+=r*r; ni+=im*im; }
    int sel = (nr>=ni)? 0 : 1;
    sSel[tid]=sel;
    sScale[tid] = sqrt((double)(2*L3[tid]+1))/sqrt(sel? ni : nr);
  }
  __syncthreads();
  if (tid < 525){
    double v = sSel[combo]? sKi[tid] : sKr[tid];
    cg[tid] = (float)(v*sScale[combo]);
  }
}

// ============================================================================
// Main fused kernel
// HID0 per-sample layout (768): l0@0(64), l1@64(64x3), l2@256(64x5), l1b@576(64x3)
// HID1 per-sample layout (1536): l0@0(128), l1@128(128x3), l2@512(128x5), l1b@1152
// ============================================================================

__device__ void lin_h(const float* __restrict__ W0, const float* __restrict__ W1,
                      const float* __restrict__ W2, const float* __restrict__ b0,
                      const float* src, float* dst, int tid)
{
  const float rs128 = 0.08838834764831845f; // 1/sqrt(128)
  // l=0: thread = (n,u), 256 items
  {
    int u=tid&63, n=tid>>6;
    const float* s=src+n*H0;
    float acc=0.f;
    #pragma unroll 8
    for (int v=0;v<64;v++) acc += s[v]*W0[v*64+u];
    dst[n*H0+u] = acc*0.125f + b0[u];
  }
  // l=1: thread = (j,u), all 4 samples; 384 items
  for (int it=tid; it<384; it+=NT){
    int u=it&127, j=it>>7;
    float a0=0.f,a1=0.f,a2=0.f,a3=0.f;
    #pragma unroll 4
    for (int v=0;v<64;v++){
      float w=W1[v*128+u];
      int so=64+v*3+j;
      a0+=w*src[so]; a1+=w*src[H0+so]; a2+=w*src[2*H0+so]; a3+=w*src[3*H0+so];
    }
    #pragma unroll 4
    for (int v=0;v<64;v++){
      float w=W1[(v+64)*128+u];
      int so=576+v*3+j;
      a0+=w*src[so]; a1+=w*src[H0+so]; a2+=w*src[2*H0+so]; a3+=w*src[3*H0+so];
    }
    int du=(u<64)?(64+u*3+j):(576+(u-64)*3+j);
    dst[du]=a0*rs128; dst[H0+du]=a1*rs128; dst[2*H0+du]=a2*rs128; dst[3*H0+du]=a3*rs128;
  }
  // l=2: thread = (j,u), all 4 samples; 320 items
  for (int it=tid; it<320; it+=NT){
    int u=it&63, j=it>>6;
    float a0=0.f,a1=0.f,a2=0.f,a3=0.f;
    #pragma unroll 4
    for (int v=0;v<64;v++){
      float w=W2[v*64+u];
      int so=256+v*5+j;
      a0+=w*src[so]; a1+=w*src[H0+so]; a2+=w*src[2*H0+so]; a3+=w*src[3*H0+so];
    }
    int du=256+u*5+j;
    dst[du]=a0*0.125f; dst[H0+du]=a1*0.125f; dst[2*H0+du]=a2*0.125f; dst[3*H0+du]=a3*0.125f;
  }
}

// stage 64x64 w transposed into s_w[v*65+u]; caller brackets with barriers
__device__ __forceinline__ void stage_w(const float* __restrict__ wp, float* s_w, int tid){
  const float4* wp4 = (const float4*)wp;
  #pragma unroll
  for (int t=0;t<4;t++){
    int i = t*NT + tid;          // float4 index in [0,1024)
    float4 w4 = wp4[i];
    int u = i>>4;
    int v0 = (i&15)*4;
    s_w[(v0  )*65+u] = w4.x;
    s_w[(v0+1)*65+u] = w4.y;
    s_w[(v0+2)*65+u] = w4.z;
    s_w[(v0+3)*65+u] = w4.w;
  }
}

// uvu path: b[j]=sum_v w[u,v]*x2[n,v,j]; oacc[OIDX+k] += sum_ij x1[i]*b[j]*K[i,j,k]
template<int D1,int D2,int D3,int O1,int O2,int OIDX,int CGO>
__device__ __forceinline__ void uvu_path(const float* __restrict__ wp,
    const float* s1, const float* s2, float* oacc,
    float* s_w, const float* s_cg, int tid)
{
  __syncthreads();               // prior users of s_w done
  stage_w(wp, s_w, tid);
  __syncthreads();
  int u = tid & 63, n = tid >> 6;
  float bacc[D2];
  #pragma unroll
  for (int j=0;j<D2;j++) bacc[j]=0.f;
  const float* x2p = s2 + n*H0 + O2;
  #pragma unroll 4
  for (int v=0;v<64;v++){
    float wv = s_w[v*65+u];
    #pragma unroll
    for (int j=0;j<D2;j++) bacc[j] += wv * x2p[v*D2+j];
  }
  float x1v[D1], tk[D3];
  #pragma unroll
  for (int i=0;i<D1;i++) x1v[i] = s1[n*H0 + O1 + u*D1 + i];
  #pragma unroll
  for (int k=0;k<D3;k++) tk[k]=0.f;
  #pragma unroll
  for (int i=0;i<D1;i++){
    #pragma unroll
    for (int j=0;j<D2;j++){
      float pr = x1v[i]*bacc[j];
      #pragma unroll
      for (int k=0;k<D3;k++) tk[k] += pr*s_cg[CGO+(i*D2+j)*D3+k];
    }
  }
  #pragma unroll
  for (int k=0;k<D3;k++) oacc[OIDX+k] += tk[k];
}

// oacc segment index: block l0->0, l1->1..3, l2->4..8, l1b->9..11
__device__ void tp_uvu_all(const float* tw, const float* s1, const float* s2, float* dst,
                           float* s_w, const float* s_cg, int tid)
{
  float oacc[12];
  #pragma unroll
  for (int i=0;i<12;i++) oacc[i]=0.f;
  uvu_path<1,1,1,  0,  0, 0,  0>(tw+ 0*4096, s1,s2,oacc,s_w,s_cg,tid);
  uvu_path<1,3,3,  0, 64, 1,  1>(tw+ 1*4096, s1,s2,oacc,s_w,s_cg,tid);
  uvu_path<1,5,5,  0,256, 4, 19>(tw+ 2*4096, s1,s2,oacc,s_w,s_cg,tid);
  uvu_path<1,3,3,  0,576, 9,  1>(tw+ 3*4096, s1,s2,oacc,s_w,s_cg,tid);
  uvu_path<3,1,3, 64,  0, 1, 10>(tw+ 4*4096, s1,s2,oacc,s_w,s_cg,tid);
  uvu_path<3,3,1, 64, 64, 0, 69>(tw+ 5*4096, s1,s2,oacc,s_w,s_cg,tid);
  uvu_path<3,3,3, 64, 64, 1, 78>(tw+ 6*4096, s1,s2,oacc,s_w,s_cg,tid);
  uvu_path<3,3,3, 64, 64, 9, 78>(tw+ 7*4096, s1,s2,oacc,s_w,s_cg,tid);
  uvu_path<5,1,5,256,  0, 4, 44>(tw+ 8*4096, s1,s2,oacc,s_w,s_cg,tid);
  uvu_path<5,3,5,256, 64, 4,150>(tw+ 9*4096, s1,s2,oacc,s_w,s_cg,tid);
  uvu_path<5,5,1,256,256, 0,300>(tw+10*4096, s1,s2,oacc,s_w,s_cg,tid);
  uvu_path<5,5,3,256,256, 1,325>(tw+11*4096, s1,s2,oacc,s_w,s_cg,tid);
  uvu_path<5,5,3,256,256, 9,325>(tw+12*4096, s1,s2,oacc,s_w,s_cg,tid);
  uvu_path<5,3,5,256,576, 4,150>(tw+13*4096, s1,s2,oacc,s_w,s_cg,tid);
  // write back with fan normalization: io0,io3 fan=192; io1,io2 fan=256
  const float f192 = 0.07216878364870323f;  // 1/sqrt(192)
  const float f256 = 0.0625f;               // 1/sqrt(256)
  int u=tid&63, n=tid>>6;
  float* dp = dst + n*H0;
  dp[u] = oacc[0]*f192;
  #pragma unroll
  for (int k=0;k<3;k++) dp[ 64+u*3+k] = oacc[1+k]*f256;
  #pragma unroll
  for (int k=0;k<5;k++) dp[256+u*5+k] = oacc[4+k]*f256;
  #pragma unroll
  for (int k=0;k<3;k++) dp[576+u*3+k] = oacc[9+k]*f192;
}

// fully-connected TP path (out mul 1: reduce over u as well)
template<int D1,int D2,int D3,int O1,int O2,int IOB,int CGO>
__device__ __forceinline__ void fc_path(const float* __restrict__ wp,
    const float* s1, const float* s2, float* s_out,
    float* s_w, const float* s_cg, int tid)
{
  __syncthreads();
  stage_w(wp, s_w, tid);
  __syncthreads();
  int u = tid & 63, n = tid >> 6;  // one wave per sample
  float bacc[D2];
  #pragma unroll
  for (int j=0;j<D2;j++) bacc[j]=0.f;
  const float* x2p = s2 + n*H0 + O2;
  #pragma unroll 4
  for (int v=0;v<64;v++){
    float wv = s_w[v*65+u];
    #pragma unroll
    for (int j=0;j<D2;j++) bacc[j] += wv * x2p[v*D2+j];
  }
  float x1v[D1], tk[D3];
  #pragma unroll
  for (int i=0;i<D1;i++) x1v[i] = s1[n*H0 + O1 + u*D1 + i];
  #pragma unroll
  for (int k=0;k<D3;k++) tk[k]=0.f;
  #pragma unroll
  for (int i=0;i<D1;i++){
    #pragma unroll
    for (int j=0;j<D2;j++){
      float pr = x1v[i]*bacc[j];
      #pragma unroll
      for (int k=0;k<D3;k++) tk[k] += pr*s_cg[CGO+(i*D2+j)*D3+k];
    }
  }
  #pragma unroll
  for (int k=0;k<D3;k++){
    float v = tk[k];
    v += __shfl_down(v, 32, 64);
    v += __shfl_down(v, 16, 64);
    v += __shfl_down(v,  8, 64);
    v += __shfl_down(v,  4, 64);
    v += __shfl_down(v,  2, 64);
    v += __shfl_down(v,  1, 64);
    if (u==0) s_out[n*6 + IOB + k] += v;
  }
}

__global__ __launch_bounds__(NT) void deeprst_main(
    const float* __restrict__ x,
    const float* __restrict__ l1W0, const float* __restrict__ l1W1,
    const float* __restrict__ l1W2, const float* __restrict__ l1b0,
    const float* __restrict__ l2W0, const float* __restrict__ l2W1,
    const float* __restrict__ l2W2, const float* __restrict__ l2b0,
    const float* __restrict__ LW0, const float* __restrict__ LW1,
    const float* __restrict__ LW2, const float* __restrict__ Lb0,
    const float* __restrict__ tpw, const float* __restrict__ tp4w,
    const float* __restrict__ cg, float* __restrict__ out)
{
  __shared__ float sA[3*TS*H0];   // 9216 floats: 3 rotating state buffers
  __shared__ float s_w[64*65];    // transposed padded path-weight tile
  __shared__ float s_cg[525];
  __shared__ float s_out[TS*6];

  const int tid = threadIdx.x;
  const int n0 = blockIdx.x * TS;
  const float rs128 = 0.08838834764831845f;
  const float rs8   = 0.3535533905932738f;

  for (int i=tid;i<525;i+=NT) s_cg[i]=cg[i];
  if (tid<TS*6) s_out[tid]=0.f;

  float* h1 = sA;              // TS*1536 floats (buffers 0+1)
  float* B2 = sA + 2*TS*H0;

  // ---- lin1: x (80) -> h1 (HID1) ----
  for (int idx=tid; idx<TS*128; idx+=NT){
    int u=idx&127, n=idx>>7;
    const float* xp = x + (n0+n)*80;
    float acc=0.f;
    #pragma unroll
    for (int v=0;v<16;v++) acc += xp[v]*l1W0[v*128+u];
    h1[n*H1+u] = acc*0.25f + l1b0[u];
  }
  for (int idx=tid; idx<TS*768; idx+=NT){
    int u=idx&255, j=(idx>>8)%3, n=idx/768;
    const float* xp = x + (n0+n)*80 + 16;
    float acc=0.f;
    #pragma unroll
    for (int v=0;v<8;v++) acc += xp[v*3+j]*l1W1[v*256+u];
    int du = (u<128)? (128+u*3+j) : (1152+(u-128)*3+j);
    h1[n*H1+du] = acc*rs8;
  }
  for (int idx=tid; idx<TS*640; idx+=NT){
    int u=idx&127, j=(idx>>7)%5, n=idx/640;
    const float* xp = x + (n0+n)*80 + 40;
    float acc=0.f;
    #pragma unroll
    for (int v=0;v<8;v++) acc += xp[v*5+j]*l1W2[v*128+u];
    h1[n*H1+512+u*5+j] = acc*rs8;
  }
  __syncthreads();

  // ---- lin2: h1 (HID1) -> B2 (HID0) ----
  {
    int u=tid&63, n=tid>>6;
    const float* s=h1+n*H1;
    float acc=0.f;
    #pragma unroll 8
    for (int v=0;v<128;v++) acc += s[v]*l2W0[v*64+u];
    B2[n*H0+u] = acc*rs128 + l2b0[u];
  }
  for (int it=tid; it<384; it+=NT){
    int u=it&127, j=it>>7;
    float a0=0.f,a1=0.f,a2=0.f,a3=0.f;
    #pragma unroll 4
    for (int v=0;v<128;v++){
      float w=l2W1[v*128+u];
      int so=128+v*3+j;
      a0+=w*h1[so]; a1+=w*h1[H1+so]; a2+=w*h1[2*H1+so]; a3+=w*h1[3*H1+so];
    }
    #pragma unroll 4
    for (int v=0;v<128;v++){
      float w=l2W1[(v+128)*128+u];
      int so=1152+v*3+j;
      a0+=w*h1[so]; a1+=w*h1[H1+so]; a2+=w*h1[2*H1+so]; a3+=w*h1[3*H1+so];
    }
    int du=(u<64)?(64+u*3+j):(576+(u-64)*3+j);
    B2[du]=a0*0.0625f; B2[H0+du]=a1*0.0625f; B2[2*H0+du]=a2*0.0625f; B2[3*H0+du]=a3*0.0625f;
  }
  for (int it=tid; it<320; it+=NT){
    int u=it&63, j=it>>6;
    float a0=0.f,a1=0.f,a2=0.f,a3=0.f;
    #pragma unroll 4
    for (int v=0;v<128;v++){
      float w=l2W2[v*64+u];
      int so=512+v*5+j;
      a0+=w*h1[so]; a1+=w*h1[H1+so]; a2+=w*h1[2*H1+so]; a3+=w*h1[3*H1+so];
    }
    int du=256+u*5+j;
    B2[du]=a0*rs128; B2[H0+du]=a1*rs128; B2[2*H0+du]=a2*rs128; B2[3*H0+du]=a3*rs128;
  }
  __syncthreads();

  // ---- 3 rounds: split -> tp_uvu -> linear ----
  float* h  = B2;
  float* u0 = sA;
  float* u1 = sA + TS*H0;
  for (int r=0;r<3;r++){
    lin_h(LW0+(3*r  )*4096, LW1+(3*r  )*16384, LW2+(3*r  )*4096, Lb0+(3*r  )*64, h, u0, tid);
    lin_h(LW0+(3*r+1)*4096, LW1+(3*r+1)*16384, LW2+(3*r+1)*4096, Lb0+(3*r+1)*64, h, u1, tid);
    __syncthreads();
    tp_uvu_all(tpw + r*14*4096, u0, u1, h, s_w, s_cg, tid); // ht overwrites h
    __syncthreads();
    lin_h(LW0+(3*r+2)*4096, LW1+(3*r+2)*16384, LW2+(3*r+2)*4096, Lb0+(3*r+2)*64, h, u0, tid);
    __syncthreads();
    float* nh=u0; u0=u1; u1=h; h=nh;
  }

  // ---- split4 + fully-connected TP ----
  lin_h(LW0+ 9*4096, LW1+ 9*16384, LW2+ 9*4096, Lb0+ 9*64, h, u0, tid);
  lin_h(LW0+10*4096, LW1+10*16384, LW2+10*4096, Lb0+10*64, h, u1, tid);
  __syncthreads();

  fc_path<1,1,1,  0,  0,0,  0>(tp4w+ 0*4096, u0,u1,s_out,s_w,s_cg,tid);
  fc_path<3,3,1, 64, 64,0, 69>(tp4w+ 1*4096, u0,u1,s_out,s_w,s_cg,tid);
  fc_path<3,3,1, 64,576,0, 69>(tp4w+ 2*4096, u0,u1,s_out,s_w,s_cg,tid);
  fc_path<5,5,1,256,256,0,300>(tp4w+ 3*4096, u0,u1,s_out,s_w,s_cg,tid);
  fc_path<3,3,1,576, 64,0, 69>(tp4w+ 4*4096, u0,u1,s_out,s_w,s_cg,tid);
  fc_path<3,3,1,576,576,0, 69>(tp4w+ 5*4096, u0,u1,s_out,s_w,s_cg,tid);
  fc_path<1,5,5,  0,256,1, 19>(tp4w+ 6*4096, u0,u1,s_out,s_w,s_cg,tid);
  fc_path<3,3,5, 64, 64,1,105>(tp4w+ 7*4096, u0,u1,s_out,s_w,s_cg,tid);
  fc_path<3,5,5, 64,256,1,225>(tp4w+ 8*4096, u0,u1,s_out,s_w,s_cg,tid);
  fc_path<3,3,5, 64,576,1,105>(tp4w+ 9*4096, u0,u1,s_out,s_w,s_cg,tid);
  fc_path<5,1,5,256,  0,1, 44>(tp4w+10*4096, u0,u1,s_out,s_w,s_cg,tid);
  fc_path<5,3,5,256, 64,1,150>(tp4w+11*4096, u0,u1,s_out,s_w,s_cg,tid);
  fc_path<5,5,5,256,256,1,400>(tp4w+12*4096, u0,u1,s_out,s_w,s_cg,tid);
  fc_path<5,3,5,256,576,1,150>(tp4w+13*4096, u0,u1,s_out,s_w,s_cg,tid);
  fc_path<3,3,5,576, 64,1,105>(tp4w+14*4096, u0,u1,s_out,s_w,s_cg,tid);
  fc_path<3,5,5,576,256,1,225>(tp4w+15*4096, u0,u1,s_out,s_w,s_cg,tid);
  fc_path<3,3,5,576,576,1,105>(tp4w+16*4096, u0,u1,s_out,s_w,s_cg,tid);
  __syncthreads();

  if (tid < TS*6){
    int n=tid/6, k=tid%6;
    float sc = (k==0)? (1.0f/sqrtf(24576.0f)) : (1.0f/sqrtf(45056.0f));
    out[(n0+n)*6+k] = s_out[tid]*sc;
  }
}

// ============================================================================
extern "C" void kernel_launch(void* const* d_in, const int* in_sizes, int n_in,
                              void* d_out, int out_size, void* d_ws, size_t ws_size,
                              hipStream_t stream)
{
  (void)n_in; (void)out_size; (void)ws_size;
  const float* x    = (const float*)d_in[0];
  const float* l1W0 = (const float*)d_in[1];
  const float* l1W1 = (const float*)d_in[2];
  const float* l1W2 = (const float*)d_in[3];
  const float* l1b0 = (const float*)d_in[4];
  const float* l2W0 = (const float*)d_in[5];
  const float* l2W1 = (const float*)d_in[6];
  const float* l2W2 = (const float*)d_in[7];
  const float* l2b0 = (const float*)d_in[8];
  const float* LW0  = (const float*)d_in[9];
  const float* LW1  = (const float*)d_in[10];
  const float* LW2  = (const float*)d_in[11];
  const float* Lb0  = (const float*)d_in[12];
  const float* tpw  = (const float*)d_in[13];
  const float* tp4w = (const float*)d_in[14];
  float* cg = (float*)d_ws;   // 525 floats; ws re-poisoned every launch -> recompute
  const int n = in_sizes[0]/80;

  cg_init_kernel<<<1, 576, 0, stream>>>(cg);
  deeprst_main<<<n/TS, NT, 0, stream>>>(x,l1W0,l1W1,l1W2,l1b0,l2W0,l2W1,l2W2,l2b0,
                                        LW0,LW1,LW2,Lb0,tpw,tp4w,cg,(float*)d_out);
}